// Round 14
// baseline (145.050 us; speedup 1.0000x reference)
//
#include <hip/hip_runtime.h>
#include <hip/hip_fp16.h>

#define NN 50000
#define FEAT 128

// Zero hist (grid-wide) + detect int64-vs-int32 edge storage (block 0).
__global__ void init_kernel(const unsigned int* ei32, int* flag, int* hist, int n) {
    int i = blockIdx.x * 256 + threadIdx.x;
    if (i < n) hist[i] = 0;
    if (blockIdx.x == 0) {
        __shared__ int ok;
        if (threadIdx.x == 0) ok = 1;
        __syncthreads();
        if (ei32[2 * threadIdx.x + 1] != 0u) ok = 0;   // benign race: all writers write 0
        __syncthreads();
        if (threadIdx.x == 0) *flag = ok;
    }
}

static __device__ __forceinline__ void load_edge(const void* ei, int is64, int E, int e,
                                                 int& src, int& dst) {
    if (is64) {
        const long long* p = (const long long*)ei;
        src = (int)p[e];
        dst = (int)p[E + e];
    } else {
        const int* p = (const int*)ei;
        src = p[e];
        dst = p[E + e];
    }
}

// ---------------- CSR build ----------------
// pass 1: per-dst rank via returning atomic; emit packed (src|dst<<16|rank<<32)
// as ONE coalesced 8B stream. hist ends up holding node degrees.
__global__ void rank_kernel(const void* ei, const int* flag, int* hist,
                            unsigned long long* __restrict__ prk, int E) {
    int base = (blockIdx.x * blockDim.x + threadIdx.x) * 4;
    if (base >= E) return;
    const int is64 = *flag;
    int n = E - base; if (n > 4) n = 4;
    int src[4], dst[4];
    #pragma unroll
    for (int i = 0; i < 4; ++i)
        if (i < n) load_edge(ei, is64, E, base + i, src[i], dst[i]);
    int r[4];
    #pragma unroll
    for (int i = 0; i < 4; ++i)
        if (i < n) r[i] = atomicAdd(&hist[dst[i]], 1);
    #pragma unroll
    for (int i = 0; i < 4; ++i)
        if (i < n)
            prk[base + i] = (unsigned long long)(unsigned int)(src[i] | (dst[i] << 16)) |
                            ((unsigned long long)(unsigned int)r[i] << 32);
}

// phase 1: per-block (256) scan -> local excl offsets + block sums + dinv (fused)
__global__ void scan_local_kernel(const int* __restrict__ hist, int* __restrict__ local_excl,
                                  int* __restrict__ bsum, float* __restrict__ dinv, int n) {
    __shared__ int sdata[256];
    int i = blockIdx.x * 256 + threadIdx.x;
    int v = (i < n) ? hist[i] : 0;
    if (i < n) dinv[i] = (v > 0) ? rsqrtf((float)v) : 0.0f;
    sdata[threadIdx.x] = v;
    __syncthreads();
    for (int d = 1; d < 256; d <<= 1) {
        int t = (threadIdx.x >= (unsigned)d) ? sdata[threadIdx.x - d] : 0;
        __syncthreads();
        sdata[threadIdx.x] += t;
        __syncthreads();
    }
    if (i < n) local_excl[i] = sdata[threadIdx.x] - v;
    if (threadIdx.x == 255) bsum[blockIdx.x] = sdata[255];
}

// phase 2 (fused): each block reduces bsum[0..blockIdx.x) -> its offset, adds.
// (no separate scan dispatch; 196-entry prefix reduction per block)
__global__ void scan_add_kernel(const int* __restrict__ local_excl, const int* __restrict__ bsum,
                                int* __restrict__ rowp, int n, int E) {
    __shared__ int sdata[256];
    int b = blockIdx.x;
    int v = ((int)threadIdx.x < b) ? bsum[threadIdx.x] : 0;   // only j < b contribute
    sdata[threadIdx.x] = v;
    __syncthreads();
    for (int d = 128; d > 0; d >>= 1) {
        if ((int)threadIdx.x < d) sdata[threadIdx.x] += sdata[threadIdx.x + d];
        __syncthreads();
    }
    int off = sdata[0];
    int i = b * 256 + threadIdx.x;
    if (i < n) rowp[i] = local_excl[i] + off;
    if (i == 0) rowp[n] = E;
}

// pass 2: placement, NO atomics, single packed input stream, 2B nt stores:
//   col[rowp[dst] + rank] = (ushort)src
__global__ void place_kernel(const unsigned long long* __restrict__ prk,
                             const int* __restrict__ rowp,
                             unsigned short* __restrict__ col, int E) {
    int base = (blockIdx.x * blockDim.x + threadIdx.x) * 4;
    if (base >= E) return;
    int n = E - base; if (n > 4) n = 4;
    unsigned long long p[4];
    #pragma unroll
    for (int i = 0; i < 4; ++i)
        if (i < n) p[i] = prk[base + i];
    int rp[4];
    #pragma unroll
    for (int i = 0; i < 4; ++i)
        if (i < n) rp[i] = rowp[(int)((p[i] >> 16) & 0xFFFF)];
    #pragma unroll
    for (int i = 0; i < 4; ++i)
        if (i < n) {
            int pos = rp[i] + (int)(p[i] >> 32);
            __builtin_nontemporal_store((unsigned short)(p[i] & 0xFFFF), &col[pos]);
        }
}

static __device__ __forceinline__ float4 relu4(float4 v) {
    v.x = fmaxf(v.x, 0.0f); v.y = fmaxf(v.y, 0.0f);
    v.z = fmaxf(v.z, 0.0f); v.w = fmaxf(v.w, 0.0f);
    return v;
}

static __device__ __forceinline__ void fma4(float4& a, float w, float4 v) {
    a.x += w * v.x; a.y += w * v.y; a.z += w * v.z; a.w += w * v.w;
}

static __device__ __forceinline__ float4 h4_to_f4(uint2 r) {
    __half2 lo = *reinterpret_cast<__half2*>(&r.x);
    __half2 hi = *reinterpret_cast<__half2*>(&r.y);
    float2 f0 = __half22float2(lo);
    float2 f1 = __half22float2(hi);
    return make_float4(f0.x, f0.y, f1.x, f1.y);
}

static __device__ __forceinline__ uint2 f4_to_h4(float4 v) {
    __half2 lo = __floats2half2_rn(v.x, v.y);
    __half2 hi = __floats2half2_rn(v.z, v.w);
    uint2 r;
    r.x = *reinterpret_cast<unsigned int*>(&lo);
    r.y = *reinterpret_cast<unsigned int*>(&hi);
    return r;
}

// convert fp32 features -> fp16 rows PRE-SCALED by dinv[node]
__global__ void cvt_f2h_kernel(const float4* __restrict__ in, const float* __restrict__ dinv,
                               uint2* __restrict__ outh, int n4) {
    int i = blockIdx.x * blockDim.x + threadIdx.x;
    if (i >= n4) return;
    float dd = dinv[i >> 5];
    float4 v = in[i];
    v.x *= dd; v.y *= dd; v.z *= dd; v.w *= dd;
    outh[i] = f4_to_h4(v);
}

// ---------------- CSR conv ----------------
// xh rows pre-scaled by dinv[src]; acc raw sums; out = relu(dinv*acc);
// OUT_HALF stores dinv*out (pre-scaled for the next layer), else fp32 out.
template <bool OUT_HALF>
__global__ void conv_h_kernel(const uint2* __restrict__ xh,
                              const int* __restrict__ row_ptr,
                              const unsigned short* __restrict__ col,
                              const float* __restrict__ dinv,
                              void* __restrict__ outbuf) {
    int gid = blockIdx.x * blockDim.x + threadIdx.x;
    int node = gid >> 5;
    int f4   = gid & 31;
    if (node >= NN) return;
    int beg = row_ptr[node];
    int end = row_ptr[node + 1];
    float dd = dinv[node];

    float4 a0 = make_float4(0.f, 0.f, 0.f, 0.f);
    float4 a1 = a0, a2 = a0, a3 = a0;

    for (int cb = beg; cb < end; cb += 32) {
        int rem = end - cb;
        if (rem > 32) rem = 32;
        int myi = (f4 < rem) ? f4 : 0;
        int pk = (int)__builtin_nontemporal_load(&col[cb + myi]);  // read-once stream

        for (int j = 0; j < rem; j += 8) {
            int i0 = j + 0, i1 = j + 1, i2 = j + 2, i3 = j + 3;
            int i4 = j + 4, i5 = j + 5, i6 = j + 6, i7 = j + 7;
            int last = rem - 1;
            int c0 = __shfl(pk, i0 < rem ? i0 : last, 32);
            int c1 = __shfl(pk, i1 < rem ? i1 : last, 32);
            int c2 = __shfl(pk, i2 < rem ? i2 : last, 32);
            int c3 = __shfl(pk, i3 < rem ? i3 : last, 32);
            int c4 = __shfl(pk, i4 < rem ? i4 : last, 32);
            int c5 = __shfl(pk, i5 < rem ? i5 : last, 32);
            int c6 = __shfl(pk, i6 < rem ? i6 : last, 32);
            int c7 = __shfl(pk, i7 < rem ? i7 : last, 32);

            float w0 = (i0 < rem) ? 1.0f : 0.0f;
            float w1 = (i1 < rem) ? 1.0f : 0.0f;
            float w2 = (i2 < rem) ? 1.0f : 0.0f;
            float w3 = (i3 < rem) ? 1.0f : 0.0f;
            float w4 = (i4 < rem) ? 1.0f : 0.0f;
            float w5 = (i5 < rem) ? 1.0f : 0.0f;
            float w6 = (i6 < rem) ? 1.0f : 0.0f;
            float w7 = (i7 < rem) ? 1.0f : 0.0f;

            uint2 r0 = xh[c0 * 32 + f4];
            uint2 r1 = xh[c1 * 32 + f4];
            uint2 r2 = xh[c2 * 32 + f4];
            uint2 r3 = xh[c3 * 32 + f4];
            uint2 r4 = xh[c4 * 32 + f4];
            uint2 r5 = xh[c5 * 32 + f4];
            uint2 r6 = xh[c6 * 32 + f4];
            uint2 r7 = xh[c7 * 32 + f4];

            fma4(a0, w0, h4_to_f4(r0));
            fma4(a1, w1, h4_to_f4(r1));
            fma4(a2, w2, h4_to_f4(r2));
            fma4(a3, w3, h4_to_f4(r3));
            fma4(a0, w4, h4_to_f4(r4));
            fma4(a1, w5, h4_to_f4(r5));
            fma4(a2, w6, h4_to_f4(r6));
            fma4(a3, w7, h4_to_f4(r7));
        }
    }

    float4 acc;
    acc.x = (a0.x + a1.x) + (a2.x + a3.x);
    acc.y = (a0.y + a1.y) + (a2.y + a3.y);
    acc.z = (a0.z + a1.z) + (a2.z + a3.z);
    acc.w = (a0.w + a1.w) + (a2.w + a3.w);
    acc.x *= dd; acc.y *= dd; acc.z *= dd; acc.w *= dd;
    acc = relu4(acc);

    if (OUT_HALF) {
        acc.x *= dd; acc.y *= dd; acc.z *= dd; acc.w *= dd;
        ((uint2*)outbuf)[node * 32 + f4] = f4_to_h4(acc);
    } else {
        ((float4*)outbuf)[node * 32 + f4] = acc;
    }
}

// ---------------- fallback (atomic) path kernels ----------------
__global__ void deg_kernel(const void* ei, const int* flag, float* deg, int E) {
    int e = blockIdx.x * blockDim.x + threadIdx.x;
    if (e >= E) return;
    int src, dst;
    load_edge(ei, *flag, E, e, src, dst);
    atomicAdd(&deg[dst], 1.0f);
}

__global__ void dinv_kernel(float* deg) {
    int i = blockIdx.x * blockDim.x + threadIdx.x;
    if (i >= NN) return;
    float d = deg[i];
    deg[i] = (d > 0.0f) ? (1.0f / sqrtf(d)) : 0.0f;
}

template <bool RELU_IN>
__global__ void conv_atomic_kernel(const float* __restrict__ xin, const void* ei, const int* flag,
                                   const float* __restrict__ dinv, float* __restrict__ yout, int E) {
    int gid = blockIdx.x * blockDim.x + threadIdx.x;
    int e  = gid >> 5;
    int f4 = gid & 31;
    if (e >= E) return;
    int src, dst;
    load_edge(ei, *flag, E, e, src, dst);
    float w = dinv[src] * dinv[dst];
    float4 v = ((const float4*)xin)[src * 32 + f4];
    if (RELU_IN) v = relu4(v);
    float* o = yout + (size_t)dst * FEAT + f4 * 4;
    atomicAdd(o + 0, v.x * w);
    atomicAdd(o + 1, v.y * w);
    atomicAdd(o + 2, v.z * w);
    atomicAdd(o + 3, v.w * w);
}

__global__ void relu_kernel(float4* buf, int n4) {
    int i = blockIdx.x * blockDim.x + threadIdx.x;
    if (i >= n4) return;
    buf[i] = relu4(buf[i]);
}

extern "C" void kernel_launch(void* const* d_in, const int* in_sizes, int n_in,
                              void* d_out, int out_size, void* d_ws, size_t ws_size,
                              hipStream_t stream) {
    const float* x  = (const float*)d_in[0];
    const void*  ei = d_in[1];
    const int E = in_sizes[1] / 2;

    float* out = (float*)d_out;
    char*  ws  = (char*)d_ws;

    const size_t feat_bytes  = (size_t)NN * FEAT * sizeof(float);
    const size_t half_bytes  = (size_t)NN * FEAT * sizeof(unsigned short);
    const int NB = (NN + 255) / 256;
    const int N4 = NN * 32;

    // ws layout (CSR fp16 path)
    const size_t OFF_FLAG = 0;
    const size_t OFF_HIST = 1024;
    const size_t OFF_DINV = OFF_HIST + (((size_t)NN * 4 + 255) & ~255ull);
    const size_t OFF_ROWP = OFF_DINV + (((size_t)NN * 4 + 255) & ~255ull);
    const size_t OFF_BSUM = OFF_ROWP + ((((size_t)NN + 1) * 4 + 255) & ~255ull);
    const size_t OFF_PRK  = OFF_BSUM + ((1024 * 4 + 255) & ~255ull);
    const size_t OFF_COL  = OFF_PRK + (((size_t)E * 8 + 255) & ~255ull);
    const size_t OFF_HA   = OFF_COL + (((size_t)E * 2 + 255) & ~255ull);
    const size_t OFF_HB   = OFF_HA + ((half_bytes + 255) & ~255ull);
    const size_t NEEDED   = OFF_HB + half_bytes;

    int* flag = (int*)(ws + OFF_FLAG);

    if (ws_size >= NEEDED) {
        int*   hist = (int*)(ws + OFF_HIST);
        float* dinv = (float*)(ws + OFF_DINV);
        int*   rowp = (int*)(ws + OFF_ROWP);
        int*   bsum = (int*)(ws + OFF_BSUM);
        unsigned long long* prk = (unsigned long long*)(ws + OFF_PRK);
        unsigned short* col = (unsigned short*)(ws + OFF_COL);
        uint2* hA   = (uint2*)(ws + OFF_HA);
        uint2* hB   = (uint2*)(ws + OFF_HB);

        init_kernel<<<NB, 256, 0, stream>>>((const unsigned int*)ei, flag, hist, NN);

        const int e4_blocks = (E / 4 + 255) / 256 + 1;
        // pass 1: ranks + packed edge stream (hist becomes degrees)
        rank_kernel<<<e4_blocks, 256, 0, stream>>>(ei, flag, hist, prk, E);
        scan_local_kernel<<<NB, 256, 0, stream>>>(hist, rowp, bsum, dinv, NN);
        // cvt needs dinv (ready after scan_local)
        cvt_f2h_kernel<<<(N4 + 255) / 256, 256, 0, stream>>>((const float4*)x, dinv, hA, N4);
        // fused bsum-prefix + add
        scan_add_kernel<<<NB, 256, 0, stream>>>(rowp, bsum, rowp, NN, E);
        // pass 2: placement (no atomics, packed stream, 2B nt stores)
        place_kernel<<<e4_blocks, 256, 0, stream>>>(prk, rowp, col, E);

        const int conv_blocks = (NN * 32 + 255) / 256;
        conv_h_kernel<true><<<conv_blocks, 256, 0, stream>>>(hA, rowp, col, dinv, hB);
        conv_h_kernel<true><<<conv_blocks, 256, 0, stream>>>(hB, rowp, col, dinv, hA);
        conv_h_kernel<false><<<conv_blocks, 256, 0, stream>>>(hA, rowp, col, dinv, out);
    } else {
        // fallback: atomic fp32 implementation
        float* dinv = (float*)(ws + 1024);
        float* y    = (float*)(ws + 262144);

        hipMemsetAsync(dinv, 0, NN * sizeof(float), stream);
        hipMemsetAsync(out, 0, feat_bytes, stream);
        hipMemsetAsync(y, 0, feat_bytes, stream);

        init_kernel<<<1, 256, 0, stream>>>((const unsigned int*)ei, flag, (int*)(ws + 512), 256);
        deg_kernel<<<(E + 255) / 256, 256, 0, stream>>>(ei, flag, dinv, E);
        dinv_kernel<<<(NN + 255) / 256, 256, 0, stream>>>(dinv);

        const int conv_blocks = (int)(((size_t)E * 32 + 255) / 256);
        conv_atomic_kernel<false><<<conv_blocks, 256, 0, stream>>>(x, ei, flag, dinv, out, E);
        conv_atomic_kernel<true><<<conv_blocks, 256, 0, stream>>>(out, ei, flag, dinv, y, E);
        hipMemsetAsync(out, 0, feat_bytes, stream);
        conv_atomic_kernel<true><<<conv_blocks, 256, 0, stream>>>(y, ei, flag, dinv, out, E);
        relu_kernel<<<(out_size / 4 + 255) / 256, 256, 0, stream>>>((float4*)out, out_size / 4);
    }
}